// Round 6
// baseline (305.989 us; speedup 1.0000x reference)
//
#include <hip/hip_runtime.h>

#define BB 512
#define SS 1024
#define TT 48
#define NSEG 4
#define SL 256         // time-steps per segment

typedef __attribute__((ext_vector_type(8))) short short8;
typedef __attribute__((ext_vector_type(4))) float float4v;
typedef unsigned uint2v __attribute__((ext_vector_type(2)));

// ---------- helpers ----------
__device__ __forceinline__ unsigned short f2bf(float x) {
    unsigned u = __float_as_uint(x);
    u += 0x7FFFu + ((u >> 16) & 1u);
    return (unsigned short)(u >> 16);
}
__device__ __forceinline__ unsigned pk2bf(float lo, float hi) {
#if __has_builtin(__builtin_amdgcn_cvt_pk_bf16_f32)
    typedef __bf16 bf16x2 __attribute__((ext_vector_type(2)));
    union { bf16x2 v; unsigned u; } cv;
    cv.v = __builtin_amdgcn_cvt_pk_bf16_f32(lo, hi);
    return cv.u;
#else
    return __builtin_amdgcn_perm(__float_as_uint(hi) + 0x8000u,
                                 __float_as_uint(lo) + 0x8000u, 0x07060302u);
#endif
}
__device__ __forceinline__ float wave_sum(float v) {
#pragma unroll
    for (int off = 32; off >= 1; off >>= 1) v += __shfl_xor(v, off, 64);
    return v;
}
__device__ __forceinline__ int wave_sum_i(int v) {
#pragma unroll
    for (int off = 32; off >= 1; off >>= 1) v += __shfl_xor(v, off, 64);
    return v;
}
__device__ __forceinline__ float wave_max(float v) {
#pragma unroll
    for (int off = 32; off >= 1; off >>= 1) v = fmaxf(v, __shfl_xor(v, off, 64));
    return v;
}
// max over lanes {i, i^16, i^32, i^48} (q-groups = rows of one column) — VALU permlanes.
__device__ __forceinline__ float xgrp_max(float m) {
#if __has_builtin(__builtin_amdgcn_permlane16_swap) && __has_builtin(__builtin_amdgcn_permlane32_swap)
    uint2v a = __builtin_amdgcn_permlane16_swap(__float_as_uint(m), __float_as_uint(m), false, false);
    m = fmaxf(__uint_as_float(a[0]), __uint_as_float(a[1]));
    uint2v b = __builtin_amdgcn_permlane32_swap(__float_as_uint(m), __float_as_uint(m), false, false);
    m = fmaxf(__uint_as_float(b[0]), __uint_as_float(b[1]));
#else
    m = fmaxf(m, __shfl_xor(m, 16, 64));
    m = fmaxf(m, __shfl_xor(m, 32, 64));
#endif
    return m;
}

// ---------- lengths ----------
__global__ __launch_bounds__(256)
void crf_len(const int* __restrict__ mask, int* __restrict__ lenArr) {
    const int b = blockIdx.x, tid = threadIdx.x;
    const int4 m4 = *(const int4*)(mask + (size_t)b * SS + tid * 4);
    int cnt = (m4.x != 0) + (m4.y != 0) + (m4.z != 0) + (m4.w != 0);
    cnt = wave_sum_i(cnt);
    __shared__ int si[4];
    if ((tid & 63) == 0) si[tid >> 6] = cnt;
    __syncthreads();
    if (tid == 0) lenArr[b] = si[0] + si[1] + si[2] + si[3];
}

// ---------- numerator: 4 blocks per batch (8 blocks/CU -> gather latency hidden) ----------
__global__ __launch_bounds__(256)
void crf_numer2(const float* __restrict__ em, const int* __restrict__ tags,
                const int* __restrict__ mask, const float* __restrict__ start_tr,
                const float* __restrict__ end_tr, const float* __restrict__ trans,
                const int* __restrict__ lenArr, float* __restrict__ numer4) {
    const int b = blockIdx.x >> 2, tid = threadIdx.x;
    const int s = (blockIdx.x & 3) * 256 + tid;
    const int* tg = tags + (size_t)b * SS;
    const float* emb = em + (size_t)b * SS * TT;
    const int tc = tg[s];
    float ns = 0.f;
    if (s >= 1) {
        if (mask[(size_t)b * SS + s])
            ns = trans[tg[s - 1] * TT + tc] + emb[(size_t)s * TT + tc];
    } else {
        ns = start_tr[tc] + emb[tc] + end_tr[tg[lenArr[b] - 1]];
    }
    ns = wave_sum(ns);
    __shared__ float sf[4];
    if ((tid & 63) == 0) sf[tid >> 6] = ns;
    __syncthreads();
    if (tid == 0) numer4[blockIdx.x] = sf[0] + sf[1] + sf[2] + sf[3];
}

// ---------- segment scan: one wave per (batch, segment), 48x48 matrix state ----------
// M_s = prod_{t in segment, t <= L-1} (diag(exp(em_t)) @ exp(trans)), columns renormed
// (per-column scale commutes through left-multiplication). C/D layout: lane (q,c),
// tile (mt,nc): M[mt*16+q*4+r][nc*16+c]. This maps directly to next step's B-operand
// (same mapping as the verified vector kernel). 18 MFMAs/step, throughput-bound.
__global__ __launch_bounds__(256, 2)
void crf_seg(const float* __restrict__ em, const float* __restrict__ trans,
             const int* __restrict__ lenArr, float* __restrict__ Mws,
             float* __restrict__ Lws) {
    __shared__ float4v ebuf[4][2][96];   // per-wave double-buffered exp(em) chunk: 12 KB

    const int tid = threadIdx.x;
    const int w = tid >> 6, lane = tid & 63;
    const int b = blockIdx.x, s = w;
    const int L = lenArr[b];
    if (L < 2 + s * SL) return;          // segment not needed; no barriers anywhere -> safe

    const int c = lane & 15, q = lane >> 4;
    const int t_start = 1 + s * SL;
    const int t_end = min(t_start + SL - 1, L - 1);
    const int steps = t_end - t_start + 1;        // in [1, 256]
    const int nfull = steps >> 3, tail = steps & 7;
    const int nch = nfull + (tail ? 1 : 0);
    const float4v Zv = {0.f, 0.f, 0.f, 0.f};

    // A fragments: exp(trans) in MFMA A layout (row = c)
    short8 afr[3][2];
#pragma unroll
    for (int mt = 0; mt < 3; ++mt) {
        const int so = mt * 16 + c;
#pragma unroll
        for (int kt = 0; kt < 2; ++kt) {
            short8 a;
#pragma unroll
            for (int i = 0; i < 8; ++i) {
                int si_;
                if (kt == 0) si_ = (i < 4) ? (q * 4 + i) : (16 + q * 4 + (i - 4));
                else         si_ = (i < 4) ? (32 + q * 4 + i) : -1;
                a[i] = (si_ >= 0) ? (short)f2bf(__expf(trans[so * TT + si_])) : (short)0;
            }
            afr[mt][kt] = a;
        }
    }

    // S = identity
    float4v S[3][3];
#pragma unroll
    for (int mt = 0; mt < 3; ++mt)
#pragma unroll
        for (int nc = 0; nc < 3; ++nc)
#pragma unroll
            for (int r = 0; r < 4; ++r)
                S[mt][nc][r] = (mt * 16 + q * 4 + r == nc * 16 + c) ? 1.f : 0.f;
    float ls[3] = {0.f, 0.f, 0.f};

    const float* emB = em + (size_t)b * SS * TT;
    float4v* eb = &ebuf[w][0][0];        // two slots of 96 float4v each

    auto stage_issue = [&](int tb, float4v& g0, float4v& g1) {
        int t0 = tb + lane / 12; t0 = t0 > 1023 ? 1023 : t0;
        g0 = *(const float4v*)(emB + (size_t)t0 * TT + (lane % 12) * 4);
        if (lane < 32) {
            const int m1 = 64 + lane;
            int t1 = tb + m1 / 12; t1 = t1 > 1023 ? 1023 : t1;
            g1 = *(const float4v*)(emB + (size_t)t1 * TT + (m1 % 12) * 4);
        }
    };
    auto stage_commit = [&](int slot, const float4v g0, const float4v g1) {
        float4v o;
        o[0] = __expf(g0[0]); o[1] = __expf(g0[1]); o[2] = __expf(g0[2]); o[3] = __expf(g0[3]);
        eb[slot * 96 + lane] = o;
        if (lane < 32) {
            float4v o1;
            o1[0] = __expf(g1[0]); o1[1] = __expf(g1[1]); o1[2] = __expf(g1[2]); o1[3] = __expf(g1[3]);
            eb[slot * 96 + 64 + lane] = o1;
        }
    };

    auto step = [&](const float4v e0, const float4v e1, const float4v e2) {
        union { short8 v; unsigned wd[4]; } B0[3], B1[3];
#pragma unroll
        for (int nc = 0; nc < 3; ++nc) {
            B0[nc].wd[0] = pk2bf(S[0][nc][0], S[0][nc][1]);
            B0[nc].wd[1] = pk2bf(S[0][nc][2], S[0][nc][3]);
            B0[nc].wd[2] = pk2bf(S[1][nc][0], S[1][nc][1]);
            B0[nc].wd[3] = pk2bf(S[1][nc][2], S[1][nc][3]);
            B1[nc].wd[0] = pk2bf(S[2][nc][0], S[2][nc][1]);
            B1[nc].wd[1] = pk2bf(S[2][nc][2], S[2][nc][3]);
            B1[nc].wd[2] = 0u; B1[nc].wd[3] = 0u;
        }
        float4v D[3][3];
#pragma unroll
        for (int nc = 0; nc < 3; ++nc)
#pragma unroll
            for (int mt = 0; mt < 3; ++mt)
                D[mt][nc] = __builtin_amdgcn_mfma_f32_16x16x32_bf16(afr[mt][0], B0[nc].v, Zv, 0, 0, 0);
#pragma unroll
        for (int nc = 0; nc < 3; ++nc)
#pragma unroll
            for (int mt = 0; mt < 3; ++mt)
                D[mt][nc] = __builtin_amdgcn_mfma_f32_16x16x32_bf16(afr[mt][1], B1[nc].v, D[mt][nc], 0, 0, 0);
#pragma unroll
        for (int nc = 0; nc < 3; ++nc) {
            S[0][nc] = D[0][nc] * e0;
            S[1][nc] = D[1][nc] * e1;
            S[2][nc] = D[2][nc] * e2;
        }
    };

    auto renorm = [&]() {
#pragma unroll
        for (int nc = 0; nc < 3; ++nc) {
            float m = fmaxf(fmaxf(S[0][nc][0], S[0][nc][1]), fmaxf(S[0][nc][2], S[0][nc][3]));
            m = fmaxf(m, fmaxf(fmaxf(S[1][nc][0], S[1][nc][1]), fmaxf(S[1][nc][2], S[1][nc][3])));
            m = fmaxf(m, fmaxf(fmaxf(S[2][nc][0], S[2][nc][1]), fmaxf(S[2][nc][2], S[2][nc][3])));
            m = fmaxf(xgrp_max(m), 1e-30f);
            ls[nc] += __logf(m);
            const float rm = __builtin_amdgcn_rcpf(m);
            S[0][nc] *= rm; S[1][nc] *= rm; S[2][nc] *= rm;
        }
    };

    // prologue: stage chunk 0 into slot 0
    {
        float4v g0, g1;
        stage_issue(t_start, g0, g1);
        stage_commit(0, g0, g1);
    }

    int slot = 0;
    for (int ch = 0; ch < nfull; ++ch) {
        const bool pf = (ch + 1 < nch);
        float4v g0, g1;
        if (pf) stage_issue(t_start + (ch + 1) * 8, g0, g1);   // HBM latency hides under MFMAs
        const float4v* rp = eb + slot * 96;
#pragma unroll
        for (int u = 0; u < 8; ++u) {
            const float4v e0 = rp[u * 12 + q];
            const float4v e1 = rp[u * 12 + 4 + q];
            const float4v e2 = rp[u * 12 + 8 + q];
            step(e0, e1, e2);
        }
        renorm();
        if (pf) stage_commit(slot ^ 1, g0, g1);
        slot ^= 1;
    }
    if (tail) {
        const float4v* rp = eb + slot * 96;
        for (int i = 0; i < tail; ++i) {
            const float4v e0 = rp[i * 12 + q];
            const float4v e1 = rp[i * 12 + 4 + q];
            const float4v e2 = rp[i * 12 + 8 + q];
            step(e0, e1, e2);
        }
    }

    // write S (f32) and per-column logscales
    float* Mout = Mws + ((size_t)b * NSEG + s) * (TT * TT);
#pragma unroll
    for (int mt = 0; mt < 3; ++mt)
#pragma unroll
        for (int r = 0; r < 4; ++r) {
            const int row = mt * 16 + q * 4 + r;
#pragma unroll
            for (int nc = 0; nc < 3; ++nc)
                Mout[row * TT + nc * 16 + c] = S[mt][nc][r];
        }
    if (q == 0) {
        float* Lout = Lws + ((size_t)b * NSEG + s) * TT;
        Lout[c] = ls[0]; Lout[16 + c] = ls[1]; Lout[32 + c] = ls[2];
    }
}

// ---------- combine: p = M_k ... M_0 p0 with per-column scale folding ----------
__global__ __launch_bounds__(64)
void crf_combine(const float* __restrict__ em, const float* __restrict__ start_tr,
                 const float* __restrict__ end_tr, const int* __restrict__ lenArr,
                 const float* __restrict__ Mws, const float* __restrict__ Lws,
                 float* __restrict__ denomArr) {
    const int b = blockIdx.x, j = threadIdx.x;
    const bool act = j < TT;
    const int L = lenArr[b];
    float v = act ? __expf(start_tr[j] + em[(size_t)b * SS * TT + j]) : 0.f;
    float lp = 0.f;
    const int k = (L - 2) >> 8;     // SL=256; negative when L==1 -> loop skipped
    __shared__ float wsh[TT];
    for (int s = 0; s <= k; ++s) {
        const float Lc = act ? Lws[((size_t)b * NSEG + s) * TT + j] : -3e38f;
        const float mx = wave_max(Lc);
        const float wv = act ? v * __expf(Lc - mx) : 0.f;
        if (act) wsh[j] = wv;
        __syncthreads();
        float acc = 0.f;
        if (act) {
            const float* Mr = Mws + (((size_t)b * NSEG + s) * TT + j) * TT;
#pragma unroll
            for (int t4i = 0; t4i < TT; t4i += 4) {
                const float4 mm = *(const float4*)(Mr + t4i);
                acc += mm.x * wsh[t4i] + mm.y * wsh[t4i + 1]
                     + mm.z * wsh[t4i + 2] + mm.w * wsh[t4i + 3];
            }
        }
        float m2 = fmaxf(wave_max(acc), 1e-30f);
        v = act ? acc * __builtin_amdgcn_rcpf(m2) : 0.f;
        lp += mx + __logf(m2);
        __syncthreads();
    }
    const float contrib = act ? v * __expf(end_tr[j]) : 0.f;
    const float tot = wave_sum(contrib);
    if (j == 0) denomArr[b] = lp + __logf(tot);
}

__global__ __launch_bounds__(64)
void crf_reduce2(const float* __restrict__ denom, const float* __restrict__ numer4,
                 float* __restrict__ out) {
    const int lane = threadIdx.x;
    float s = 0.f;
    for (int i = lane; i < BB; i += 64) {
        const float n = numer4[4 * i] + numer4[4 * i + 1] + numer4[4 * i + 2] + numer4[4 * i + 3];
        s += denom[i] - n;
    }
    s = wave_sum(s);
    if (lane == 0) out[0] = s * (1.0f / (float)BB);
}

extern "C" void kernel_launch(void* const* d_in, const int* in_sizes, int n_in,
                              void* d_out, int out_size, void* d_ws, size_t ws_size,
                              hipStream_t stream) {
    const float* emissions = (const float*)d_in[0];
    const int*   tags      = (const int*)d_in[1];
    const int*   mask      = (const int*)d_in[2];
    const float* start_tr  = (const float*)d_in[3];
    const float* end_tr    = (const float*)d_in[4];
    const float* trans     = (const float*)d_in[5];

    char* ws = (char*)d_ws;
    float* denom  = (float*)ws;               // 2 KB
    float* numer4 = (float*)(ws + 2048);      // 8 KB (512*4)
    int*   lenA   = (int*)(ws + 10240);       // 2 KB
    float* Lws    = (float*)(ws + 12288);     // 384 KB (512*4*48)
    float* Mws    = (float*)(ws + 405504);    // 18 MB  (512*4*48*48 f32)

    crf_len<<<BB, 256, 0, stream>>>(mask, lenA);
    crf_numer2<<<BB * 4, 256, 0, stream>>>(emissions, tags, mask, start_tr, end_tr,
                                           trans, lenA, numer4);
    crf_seg<<<BB, 256, 0, stream>>>(emissions, trans, lenA, Mws, Lws);
    crf_combine<<<BB, 64, 0, stream>>>(emissions, start_tr, end_tr, lenA, Mws, Lws, denom);
    crf_reduce2<<<1, 64, 0, stream>>>(denom, numer4, (float*)d_out);
}

// Round 7
// 302.344 us; speedup vs baseline: 1.0121x; 1.0121x over previous
//
#include <hip/hip_runtime.h>

#define BB 512
#define SS 1024
#define TT 48
#define NSEG 8
#define SL 128         // time-steps per segment

typedef __attribute__((ext_vector_type(8))) short short8;
typedef __attribute__((ext_vector_type(4))) float float4v;
typedef unsigned uint2v __attribute__((ext_vector_type(2)));

// ---------- helpers ----------
__device__ __forceinline__ unsigned short f2bf(float x) {
    unsigned u = __float_as_uint(x);
    u += 0x7FFFu + ((u >> 16) & 1u);
    return (unsigned short)(u >> 16);
}
__device__ __forceinline__ float bflo(unsigned u) { return __uint_as_float(u << 16); }
__device__ __forceinline__ float bfhi(unsigned u) { return __uint_as_float(u & 0xFFFF0000u); }
__device__ __forceinline__ unsigned pk2bf(float lo, float hi) {
#if __has_builtin(__builtin_amdgcn_cvt_pk_bf16_f32)
    typedef __bf16 bf16x2 __attribute__((ext_vector_type(2)));
    union { bf16x2 v; unsigned u; } cv;
    cv.v = __builtin_amdgcn_cvt_pk_bf16_f32(lo, hi);
    return cv.u;
#else
    return __builtin_amdgcn_perm(__float_as_uint(hi) + 0x8000u,
                                 __float_as_uint(lo) + 0x8000u, 0x07060302u);
#endif
}
__device__ __forceinline__ float wave_sum(float v) {
#pragma unroll
    for (int off = 32; off >= 1; off >>= 1) v += __shfl_xor(v, off, 64);
    return v;
}
__device__ __forceinline__ int wave_sum_i(int v) {
#pragma unroll
    for (int off = 32; off >= 1; off >>= 1) v += __shfl_xor(v, off, 64);
    return v;
}
__device__ __forceinline__ float wave_max(float v) {
#pragma unroll
    for (int off = 32; off >= 1; off >>= 1) v = fmaxf(v, __shfl_xor(v, off, 64));
    return v;
}
// max over lanes {i, i^16, i^32, i^48} (q-groups = rows of one column) — VALU permlanes.
__device__ __forceinline__ float xgrp_max(float m) {
#if __has_builtin(__builtin_amdgcn_permlane16_swap) && __has_builtin(__builtin_amdgcn_permlane32_swap)
    uint2v a = __builtin_amdgcn_permlane16_swap(__float_as_uint(m), __float_as_uint(m), false, false);
    m = fmaxf(__uint_as_float(a[0]), __uint_as_float(a[1]));
    uint2v b = __builtin_amdgcn_permlane32_swap(__float_as_uint(m), __float_as_uint(m), false, false);
    m = fmaxf(__uint_as_float(b[0]), __uint_as_float(b[1]));
#else
    m = fmaxf(m, __shfl_xor(m, 16, 64));
    m = fmaxf(m, __shfl_xor(m, 32, 64));
#endif
    return m;
}

// ---------- lengths ----------
__global__ __launch_bounds__(256)
void crf_len(const int* __restrict__ mask, int* __restrict__ lenArr) {
    const int b = blockIdx.x, tid = threadIdx.x;
    const int4 m4 = *(const int4*)(mask + (size_t)b * SS + tid * 4);
    int cnt = (m4.x != 0) + (m4.y != 0) + (m4.z != 0) + (m4.w != 0);
    cnt = wave_sum_i(cnt);
    __shared__ int si[4];
    if ((tid & 63) == 0) si[tid >> 6] = cnt;
    __syncthreads();
    if (tid == 0) lenArr[b] = si[0] + si[1] + si[2] + si[3];
}

// ---------- numerator: 4 blocks per batch (8 blocks/CU -> gather latency hidden) ----------
__global__ __launch_bounds__(256)
void crf_numer2(const float* __restrict__ em, const int* __restrict__ tags,
                const int* __restrict__ mask, const float* __restrict__ start_tr,
                const float* __restrict__ end_tr, const float* __restrict__ trans,
                const int* __restrict__ lenArr, float* __restrict__ numer4) {
    const int b = blockIdx.x >> 2, tid = threadIdx.x;
    const int s = (blockIdx.x & 3) * 256 + tid;
    const int* tg = tags + (size_t)b * SS;
    const float* emb = em + (size_t)b * SS * TT;
    const int tc = tg[s];
    float ns = 0.f;
    if (s >= 1) {
        if (mask[(size_t)b * SS + s])
            ns = trans[tg[s - 1] * TT + tc] + emb[(size_t)s * TT + tc];
    } else {
        ns = start_tr[tc] + emb[tc] + end_tr[tg[lenArr[b] - 1]];
    }
    ns = wave_sum(ns);
    __shared__ float sf[4];
    if ((tid & 63) == 0) sf[tid >> 6] = ns;
    __syncthreads();
    if (tid == 0) numer4[blockIdx.x] = sf[0] + sf[1] + sf[2] + sf[3];
}

// ---------- segment scan: one wave per (batch, segment), 48x48 matrix state ----------
// M_s = prod_{t in segment, t <= L-1} (diag(exp(em_t)) @ exp(trans)), columns renormed
// (per-column scale commutes through left-multiplication). C/D layout: lane (q,c),
// tile (mt,nc): M[mt*16+q*4+r][nc*16+c] -> maps directly to next step's B-operand.
// 18 MFMAs/step. NSEG=8, 2 blocks/batch, 4 blocks/CU -> up to 4 waves/SIMD feeding
// the matrix pipe. Output stored bf16 (S is bf16-quantized every step anyway).
__global__ __launch_bounds__(256, 4)
void crf_seg(const float* __restrict__ em, const float* __restrict__ trans,
             const int* __restrict__ lenArr, unsigned short* __restrict__ Mws,
             float* __restrict__ Lws) {
    __shared__ float4v ebuf[4][2][96];   // per-wave double-buffered exp(em) chunk: 12 KB

    const int tid = threadIdx.x;
    const int w = tid >> 6, lane = tid & 63;
    const int b = blockIdx.x >> 1;
    const int s = (blockIdx.x & 1) * 4 + w;       // segment id 0..7
    const int L = lenArr[b];
    if (L < 2 + s * SL) return;          // segment not needed; no barriers anywhere -> safe

    const int c = lane & 15, q = lane >> 4;
    const int t_start = 1 + s * SL;
    const int t_end = min(t_start + SL - 1, L - 1);
    const int steps = t_end - t_start + 1;        // in [1, 128]
    const int nfull = steps >> 3, tail = steps & 7;
    const int nch = nfull + (tail ? 1 : 0);
    const float4v Zv = {0.f, 0.f, 0.f, 0.f};

    // A fragments: exp(trans) in MFMA A layout (row = c)
    short8 afr[3][2];
#pragma unroll
    for (int mt = 0; mt < 3; ++mt) {
        const int so = mt * 16 + c;
#pragma unroll
        for (int kt = 0; kt < 2; ++kt) {
            short8 a;
#pragma unroll
            for (int i = 0; i < 8; ++i) {
                int si_;
                if (kt == 0) si_ = (i < 4) ? (q * 4 + i) : (16 + q * 4 + (i - 4));
                else         si_ = (i < 4) ? (32 + q * 4 + i) : -1;
                a[i] = (si_ >= 0) ? (short)f2bf(__expf(trans[so * TT + si_])) : (short)0;
            }
            afr[mt][kt] = a;
        }
    }

    // S = identity
    float4v S[3][3];
#pragma unroll
    for (int mt = 0; mt < 3; ++mt)
#pragma unroll
        for (int nc = 0; nc < 3; ++nc)
#pragma unroll
            for (int r = 0; r < 4; ++r)
                S[mt][nc][r] = (mt * 16 + q * 4 + r == nc * 16 + c) ? 1.f : 0.f;
    float ls[3] = {0.f, 0.f, 0.f};

    const float* emB = em + (size_t)b * SS * TT;
    float4v* eb = &ebuf[w][0][0];        // two slots of 96 float4v each

    auto stage_issue = [&](int tb, float4v& g0, float4v& g1) {
        int t0 = tb + lane / 12; t0 = t0 > 1023 ? 1023 : t0;
        g0 = *(const float4v*)(emB + (size_t)t0 * TT + (lane % 12) * 4);
        if (lane < 32) {
            const int m1 = 64 + lane;
            int t1 = tb + m1 / 12; t1 = t1 > 1023 ? 1023 : t1;
            g1 = *(const float4v*)(emB + (size_t)t1 * TT + (m1 % 12) * 4);
        }
    };
    auto stage_commit = [&](int slot, const float4v g0, const float4v g1) {
        float4v o;
        o[0] = __expf(g0[0]); o[1] = __expf(g0[1]); o[2] = __expf(g0[2]); o[3] = __expf(g0[3]);
        eb[slot * 96 + lane] = o;
        if (lane < 32) {
            float4v o1;
            o1[0] = __expf(g1[0]); o1[1] = __expf(g1[1]); o1[2] = __expf(g1[2]); o1[3] = __expf(g1[3]);
            eb[slot * 96 + 64 + lane] = o1;
        }
    };

    auto step = [&](const float4v e0, const float4v e1, const float4v e2) {
        union { short8 v; unsigned wd[4]; } B0[3], B1[3];
#pragma unroll
        for (int nc = 0; nc < 3; ++nc) {
            B0[nc].wd[0] = pk2bf(S[0][nc][0], S[0][nc][1]);
            B0[nc].wd[1] = pk2bf(S[0][nc][2], S[0][nc][3]);
            B0[nc].wd[2] = pk2bf(S[1][nc][0], S[1][nc][1]);
            B0[nc].wd[3] = pk2bf(S[1][nc][2], S[1][nc][3]);
            B1[nc].wd[0] = pk2bf(S[2][nc][0], S[2][nc][1]);
            B1[nc].wd[1] = pk2bf(S[2][nc][2], S[2][nc][3]);
            B1[nc].wd[2] = 0u; B1[nc].wd[3] = 0u;
        }
        float4v D[3][3];
#pragma unroll
        for (int nc = 0; nc < 3; ++nc)
#pragma unroll
            for (int mt = 0; mt < 3; ++mt)
                D[mt][nc] = __builtin_amdgcn_mfma_f32_16x16x32_bf16(afr[mt][0], B0[nc].v, Zv, 0, 0, 0);
#pragma unroll
        for (int nc = 0; nc < 3; ++nc)
#pragma unroll
            for (int mt = 0; mt < 3; ++mt)
                D[mt][nc] = __builtin_amdgcn_mfma_f32_16x16x32_bf16(afr[mt][1], B1[nc].v, D[mt][nc], 0, 0, 0);
#pragma unroll
        for (int nc = 0; nc < 3; ++nc) {
            S[0][nc] = D[0][nc] * e0;
            S[1][nc] = D[1][nc] * e1;
            S[2][nc] = D[2][nc] * e2;
        }
    };

    auto renorm = [&]() {
#pragma unroll
        for (int nc = 0; nc < 3; ++nc) {
            float m = fmaxf(fmaxf(S[0][nc][0], S[0][nc][1]), fmaxf(S[0][nc][2], S[0][nc][3]));
            m = fmaxf(m, fmaxf(fmaxf(S[1][nc][0], S[1][nc][1]), fmaxf(S[1][nc][2], S[1][nc][3])));
            m = fmaxf(m, fmaxf(fmaxf(S[2][nc][0], S[2][nc][1]), fmaxf(S[2][nc][2], S[2][nc][3])));
            m = fmaxf(xgrp_max(m), 1e-30f);
            ls[nc] += __logf(m);
            const float rm = __builtin_amdgcn_rcpf(m);
            S[0][nc] *= rm; S[1][nc] *= rm; S[2][nc] *= rm;
        }
    };

    // prologue: stage chunk 0 into slot 0
    {
        float4v g0, g1;
        stage_issue(t_start, g0, g1);
        stage_commit(0, g0, g1);
    }

    int slot = 0;
    for (int ch = 0; ch < nfull; ++ch) {
        const bool pf = (ch + 1 < nch);
        float4v g0, g1;
        if (pf) stage_issue(t_start + (ch + 1) * 8, g0, g1);   // HBM latency hides under MFMAs
        const float4v* rp = eb + slot * 96;
#pragma unroll
        for (int u = 0; u < 8; ++u) {
            const float4v e0 = rp[u * 12 + q];
            const float4v e1 = rp[u * 12 + 4 + q];
            const float4v e2 = rp[u * 12 + 8 + q];
            step(e0, e1, e2);
        }
        renorm();
        if (pf) stage_commit(slot ^ 1, g0, g1);
        slot ^= 1;
    }
    if (tail) {
        const float4v* rp = eb + slot * 96;
        for (int i = 0; i < tail; ++i) {
            const float4v e0 = rp[i * 12 + q];
            const float4v e1 = rp[i * 12 + 4 + q];
            const float4v e2 = rp[i * 12 + 8 + q];
            step(e0, e1, e2);
        }
    }

    // write S (bf16) and per-column logscales
    unsigned short* Mout = Mws + ((size_t)b * NSEG + s) * (TT * TT);
#pragma unroll
    for (int mt = 0; mt < 3; ++mt)
#pragma unroll
        for (int r = 0; r < 4; ++r) {
            const int row = mt * 16 + q * 4 + r;
#pragma unroll
            for (int nc = 0; nc < 3; ++nc)
                Mout[row * TT + nc * 16 + c] = f2bf(S[mt][nc][r]);
        }
    if (q == 0) {
        float* Lout = Lws + ((size_t)b * NSEG + s) * TT;
        Lout[c] = ls[0]; Lout[16 + c] = ls[1]; Lout[32 + c] = ls[2];
    }
}

// ---------- combine: p = M_k ... M_0 p0 with per-column scale folding ----------
__global__ __launch_bounds__(64)
void crf_combine(const float* __restrict__ em, const float* __restrict__ start_tr,
                 const float* __restrict__ end_tr, const int* __restrict__ lenArr,
                 const unsigned short* __restrict__ Mws, const float* __restrict__ Lws,
                 float* __restrict__ denomArr) {
    const int b = blockIdx.x, j = threadIdx.x;
    const bool act = j < TT;
    const int L = lenArr[b];
    float v = act ? __expf(start_tr[j] + em[(size_t)b * SS * TT + j]) : 0.f;
    float lp = 0.f;
    const int k = (L - 2) >> 7;     // SL=128; negative when L==1 -> loop skipped
    __shared__ float wsh[TT];
    for (int s = 0; s <= k; ++s) {
        const float Lc = act ? Lws[((size_t)b * NSEG + s) * TT + j] : -3e38f;
        const float mx = wave_max(Lc);
        const float wv = act ? v * __expf(Lc - mx) : 0.f;
        if (act) wsh[j] = wv;
        __syncthreads();
        float acc = 0.f;
        if (act) {
            const unsigned short* Mr = Mws + (((size_t)b * NSEG + s) * TT + j) * TT;
#pragma unroll
            for (int t4i = 0; t4i < TT; t4i += 4) {
                const uint2 mm = *(const uint2*)(Mr + t4i);
                acc += bflo(mm.x) * wsh[t4i]     + bfhi(mm.x) * wsh[t4i + 1]
                     + bflo(mm.y) * wsh[t4i + 2] + bfhi(mm.y) * wsh[t4i + 3];
            }
        }
        float m2 = fmaxf(wave_max(acc), 1e-30f);
        v = act ? acc * __builtin_amdgcn_rcpf(m2) : 0.f;
        lp += mx + __logf(m2);
        __syncthreads();
    }
    const float contrib = act ? v * __expf(end_tr[j]) : 0.f;
    const float tot = wave_sum(contrib);
    if (j == 0) denomArr[b] = lp + __logf(tot);
}

__global__ __launch_bounds__(64)
void crf_reduce2(const float* __restrict__ denom, const float* __restrict__ numer4,
                 float* __restrict__ out) {
    const int lane = threadIdx.x;
    float s = 0.f;
    for (int i = lane; i < BB; i += 64) {
        const float n = numer4[4 * i] + numer4[4 * i + 1] + numer4[4 * i + 2] + numer4[4 * i + 3];
        s += denom[i] - n;
    }
    s = wave_sum(s);
    if (lane == 0) out[0] = s * (1.0f / (float)BB);
}

extern "C" void kernel_launch(void* const* d_in, const int* in_sizes, int n_in,
                              void* d_out, int out_size, void* d_ws, size_t ws_size,
                              hipStream_t stream) {
    const float* emissions = (const float*)d_in[0];
    const int*   tags      = (const int*)d_in[1];
    const int*   mask      = (const int*)d_in[2];
    const float* start_tr  = (const float*)d_in[3];
    const float* end_tr    = (const float*)d_in[4];
    const float* trans     = (const float*)d_in[5];

    char* ws = (char*)d_ws;
    float*          denom  = (float*)ws;                // 2 KB
    float*          numer4 = (float*)(ws + 2048);       // 8 KB (512*4)
    int*            lenA   = (int*)(ws + 10240);        // 2 KB
    float*          Lws    = (float*)(ws + 12288);      // 768 KB (512*8*48 f32)
    unsigned short* Mws    = (unsigned short*)(ws + 798720);  // 18.9 MB (512*8*48*48 bf16)

    crf_len<<<BB, 256, 0, stream>>>(mask, lenA);
    crf_numer2<<<BB * 4, 256, 0, stream>>>(emissions, tags, mask, start_tr, end_tr,
                                           trans, lenA, numer4);
    crf_seg<<<BB * 2, 256, 0, stream>>>(emissions, trans, lenA, Mws, Lws);
    crf_combine<<<BB, 64, 0, stream>>>(emissions, start_tr, end_tr, lenA, Mws, Lws, denom);
    crf_reduce2<<<1, 64, 0, stream>>>(denom, numer4, (float*)d_out);
}